// Round 1
// baseline (20065.244 us; speedup 1.0000x reference)
//
#include <hip/hip_runtime.h>
#include <math.h>

// ---------------------------------------------------------------------------
// Seq2seq (GRU enc + attn GRU dec, teacher forcing) -> mean NLL scalar.
// Decomposition:
//   K1a: enc_gi[512][3072] = enc_emb[input] @ enc_W_ih^T + b_ih      (GEMM)
//   K1b: attn_e[512][512]  = dec_emb[dec_in] @ attn_W[:, :H]^T + attn_b
//   K1c: comb_e[512][1024] = dec_emb[dec_in] @ comb_W[:, :H]^T + comb_b
//   K2 : persistent encoder recurrence (512 steps, grid barrier/step)
//   K3 : M[1024][512] = comb_W[:, H:] @ enc_outs^T                   (GEMM)
//   K4 : persistent decoder recurrence (512 steps, 3 barriers/step)
//   K5 : logits GEMM [512,32000] + fused per-row (max, sumexp) partials
//   K6 : combine partials -> lse -> mean NLL -> d_out[0]
// ---------------------------------------------------------------------------

#define H 1024
#define T 512
#define V 32000

// ------------------------- grid barrier (device scope) ---------------------
// counters: group g at uint index g*64 (256B apart), global at uint index 512.
// monotonic; target = step * 8 (8 groups of 32 blocks).
__device__ __forceinline__ void grid_barrier(unsigned* cnts, int step) {
    __syncthreads();
    if (threadIdx.x == 0) {
        unsigned* grp = cnts + ((blockIdx.x >> 5) * 64);
        unsigned* gl  = cnts + 512;
        unsigned old = __hip_atomic_fetch_add(grp, 1u, __ATOMIC_ACQ_REL,
                                              __HIP_MEMORY_SCOPE_AGENT);
        if ((old & 31u) == 31u)
            __hip_atomic_fetch_add(gl, 1u, __ATOMIC_RELEASE,
                                   __HIP_MEMORY_SCOPE_AGENT);
        while (__hip_atomic_load(gl, __ATOMIC_RELAXED,
                                 __HIP_MEMORY_SCOPE_AGENT) < (unsigned)(step * 8)) {
            __builtin_amdgcn_s_sleep(1);
        }
        __builtin_amdgcn_fence(__ATOMIC_ACQUIRE, "agent");
    }
    __syncthreads();
}

__device__ __forceinline__ float sigmoidf_(float x) { return 1.f / (1.f + expf(-x)); }

// ------------------------- generic tiled GEMM ------------------------------
// C[t,n] = sum_k Xrow(t)[k] * Wrow(n)[k] (+ bias[n])
// Xrow(t): gmode 0 -> X + t*xs + xo ; 1 -> X + idx[t]*xs + xo ;
//          2 -> X + ((t==0)?0:idx[t-1])*xs + xo   (teacher-forced dec input)
__global__ __launch_bounds__(256) void gemm_tn(
    const float* __restrict__ X, int xs, int xo,
    const int* __restrict__ gidx, int gmode,
    const float* __restrict__ W, int wsd, int wo,
    const float* __restrict__ bias,
    float* __restrict__ C, int cs, int K)
{
    __shared__ float A_lds[32][64];
    __shared__ float B_lds[32][64];
    const int tid = threadIdx.x;
    const int tx = tid & 15, ty = tid >> 4;
    const int n0 = blockIdx.x * 64, t0 = blockIdx.y * 64;
    float acc[4][4] = {};

    for (int k0 = 0; k0 < K; k0 += 32) {
        #pragma unroll
        for (int q = 0; q < 2; ++q) {
            int f4 = tid + q * 256;          // 0..511
            int row = f4 >> 3, c4 = f4 & 7;
            int trow = t0 + row;
            const float* xr;
            if (gmode == 0)      xr = X + (size_t)trow * xs + xo;
            else if (gmode == 1) xr = X + (size_t)gidx[trow] * xs + xo;
            else { int tok = (trow == 0) ? 0 : gidx[trow - 1];
                   xr = X + (size_t)tok * xs + xo; }
            float4 a = *(const float4*)(xr + k0 + c4 * 4);
            A_lds[c4*4+0][row] = a.x; A_lds[c4*4+1][row] = a.y;
            A_lds[c4*4+2][row] = a.z; A_lds[c4*4+3][row] = a.w;
            const float* wr = W + (size_t)(n0 + row) * wsd + wo;
            float4 b = *(const float4*)(wr + k0 + c4 * 4);
            B_lds[c4*4+0][row] = b.x; B_lds[c4*4+1][row] = b.y;
            B_lds[c4*4+2][row] = b.z; B_lds[c4*4+3][row] = b.w;
        }
        __syncthreads();
        #pragma unroll
        for (int kk = 0; kk < 32; ++kk) {
            float4 a = *(const float4*)&A_lds[kk][ty * 4];
            float4 b = *(const float4*)&B_lds[kk][tx * 4];
            float av[4] = {a.x, a.y, a.z, a.w};
            float bv[4] = {b.x, b.y, b.z, b.w};
            #pragma unroll
            for (int i = 0; i < 4; ++i)
                #pragma unroll
                for (int j = 0; j < 4; ++j)
                    acc[i][j] = fmaf(av[i], bv[j], acc[i][j]);
        }
        __syncthreads();
    }
    float bj[4];
    #pragma unroll
    for (int j = 0; j < 4; ++j) bj[j] = bias ? bias[n0 + tx * 4 + j] : 0.f;
    #pragma unroll
    for (int i = 0; i < 4; ++i)
        #pragma unroll
        for (int j = 0; j < 4; ++j)
            C[(size_t)(t0 + ty * 4 + i) * cs + n0 + tx * 4 + j] = acc[i][j] + bj[j];
}

// ------------------------- encoder recurrence ------------------------------
// 256 blocks x 512 threads; block b owns h indices [4b, 4b+4).
// LDS-resident W_hh rows (12 x 1024). 1 grid barrier per step.
__global__ __launch_bounds__(512) void enc_seq(
    const float* __restrict__ Whh, const float* __restrict__ bhh,
    const float* __restrict__ gi,          // enc_gi [512][3072]
    float* __restrict__ enc_outs,          // [512][1024]
    const float* __restrict__ zero_row,
    unsigned* __restrict__ bar)
{
    __shared__ float4 w4[12 * 256];
    __shared__ float h_lds[1024];
    __shared__ float gh_lds[12];
    __shared__ float bias_lds[12];
    const int tid = threadIdx.x, bid = blockIdx.x;
    const int j0 = bid * 4;
    for (int i = tid; i < 12 * 256; i += 512) {
        int r = i >> 8, c = i & 255;
        int grow = (r >> 2) * 1024 + j0 + (r & 3);
        w4[i] = *(const float4*)(Whh + (size_t)grow * 1024 + c * 4);
    }
    if (tid < 12) bias_lds[tid] = bhh[(tid >> 2) * 1024 + j0 + (tid & 3)];
    __syncthreads();

    const int wid = tid >> 6, lane = tid & 63;
    for (int t = 0; t < T; ++t) {
        const float* hsrc = (t == 0) ? zero_row : (enc_outs + (size_t)(t - 1) * 1024);
        if (tid < 256) ((float4*)h_lds)[tid] = ((const float4*)hsrc)[tid];
        // prefetch gi for the gate combine (overlaps with dots)
        float gir = 0.f, giz = 0.f, gin = 0.f;
        if (tid < 4) {
            const float* gr = gi + (size_t)t * 3072 + j0 + tid;
            gir = gr[0]; giz = gr[1024]; gin = gr[2048];
        }
        __syncthreads();
        for (int rr = wid; rr < 12; rr += 8) {
            const float4* wrow = w4 + rr * 256;
            float acc = 0.f;
            #pragma unroll
            for (int i = 0; i < 4; ++i) {
                float4 wv = wrow[lane + 64 * i];
                float4 hv = ((const float4*)h_lds)[lane + 64 * i];
                acc += wv.x*hv.x + wv.y*hv.y + wv.z*hv.z + wv.w*hv.w;
            }
            #pragma unroll
            for (int o = 32; o; o >>= 1) acc += __shfl_xor(acc, o);
            if (lane == 0) gh_lds[rr] = acc + bias_lds[rr];
        }
        __syncthreads();
        if (tid < 4) {
            float r = sigmoidf_(gir + gh_lds[tid]);
            float z = sigmoidf_(giz + gh_lds[4 + tid]);
            float n = tanhf(gin + r * gh_lds[8 + tid]);
            float hp = h_lds[j0 + tid];
            enc_outs[(size_t)t * 1024 + j0 + tid] = (1.f - z) * n + z * hp;
        }
        if (t < T - 1) grid_barrier(bar, t + 1);
    }
}

// ------------------------- decoder recurrence ------------------------------
// 256 blocks x 512 threads; block b owns h indices [4b,4b+4) and s indices
// [2b,2b+2). LDS-resident: dec_W_ih, dec_W_hh (12 rows each), attn_W h-half
// (2 rows), M (4 rows). 3 grid barriers per step.
__global__ __launch_bounds__(512) void dec_seq(
    const float* __restrict__ Wih, const float* __restrict__ Whh,
    const float* __restrict__ bih, const float* __restrict__ bhh,
    const float* __restrict__ attnW,   // [512][2048]
    const float* __restrict__ attn_e,  // [512][512]
    const float* __restrict__ comb_e,  // [512][1024]
    const float* __restrict__ M,       // [1024][512]
    const float* __restrict__ enc_outs,
    float* __restrict__ H2,            // [512][1024]
    float* __restrict__ s_buf, float* __restrict__ x_buf,
    unsigned* __restrict__ bar)
{
    __shared__ float4 wih4[12 * 256];
    __shared__ float4 whh4[12 * 256];
    __shared__ float4 aw4[2 * 256];
    __shared__ float4 m4[4 * 128];
    __shared__ float h_lds[1024];
    __shared__ float x_lds[1024];
    __shared__ float p_lds[512];
    __shared__ float gh_lds[12], gi_lds[12];
    __shared__ float bih_lds[12], bhh_lds[12];
    __shared__ float red[8];
    __shared__ float mx_sh, sum_sh;

    const int tid = threadIdx.x, bid = blockIdx.x;
    const int j0 = bid * 4, l0 = bid * 2;
    for (int i = tid; i < 12 * 256; i += 512) {
        int r = i >> 8, c = i & 255;
        int grow = (r >> 2) * 1024 + j0 + (r & 3);
        wih4[i] = *(const float4*)(Wih + (size_t)grow * 1024 + c * 4);
        whh4[i] = *(const float4*)(Whh + (size_t)grow * 1024 + c * 4);
    }
    for (int i = tid; i < 2 * 256; i += 512) {
        int r = i >> 8, c = i & 255;
        aw4[i] = *(const float4*)(attnW + (size_t)(l0 + r) * 2048 + 1024 + c * 4);
    }
    for (int i = tid; i < 4 * 128; i += 512) {
        int r = i >> 7, c = i & 127;
        m4[i] = *(const float4*)(M + (size_t)(j0 + r) * 512 + c * 4);
    }
    if (tid < 12) {
        int grow = (tid >> 2) * 1024 + j0 + (tid & 3);
        bih_lds[tid] = bih[grow]; bhh_lds[tid] = bhh[grow];
    }
    __syncthreads();

    const int wid = tid >> 6, lane = tid & 63;
    for (int t = 0; t < T; ++t) {
        // -------- phase A: s = attn_e + A_h@h ; gh = W_hh@h + b_hh --------
        const float* hsrc = (t == 0) ? (enc_outs + (size_t)(T - 1) * 1024)
                                     : (H2 + (size_t)(t - 1) * 1024);
        if (tid < 256) ((float4*)h_lds)[tid] = ((const float4*)hsrc)[tid];
        float ae = 0.f;
        if ((wid == 4 || wid == 5) && lane == 0)
            ae = attn_e[(size_t)t * 512 + l0 + (wid - 4)];
        __syncthreads();
        for (int rr = wid; rr < 14; rr += 8) {
            const float4* wrow = (rr < 12) ? (whh4 + rr * 256) : (aw4 + (rr - 12) * 256);
            float acc = 0.f;
            #pragma unroll
            for (int i = 0; i < 4; ++i) {
                float4 wv = wrow[lane + 64 * i];
                float4 hv = ((const float4*)h_lds)[lane + 64 * i];
                acc += wv.x*hv.x + wv.y*hv.y + wv.z*hv.z + wv.w*hv.w;
            }
            #pragma unroll
            for (int o = 32; o; o >>= 1) acc += __shfl_xor(acc, o);
            if (lane == 0) {
                if (rr < 12) gh_lds[rr] = acc + bhh_lds[rr];
                else         s_buf[l0 + (rr - 12)] = acc + ae;
            }
        }
        grid_barrier(bar, 3 * t + 1);
        // -------- phase B: softmax(s) ; x = relu(comb_e + M@aw) -----------
        if (tid < 128) ((float4*)p_lds)[tid] = ((const float4*)s_buf)[tid];
        float ce = 0.f;
        if (wid < 4 && lane == 0) ce = comb_e[(size_t)t * 1024 + j0 + wid];
        __syncthreads();
        float v = p_lds[tid];
        float mv = v;
        #pragma unroll
        for (int o = 32; o; o >>= 1) mv = fmaxf(mv, __shfl_xor(mv, o));
        if (lane == 0) red[wid] = mv;
        __syncthreads();
        if (tid == 0) {
            float m2 = red[0];
            for (int w = 1; w < 8; ++w) m2 = fmaxf(m2, red[w]);
            mx_sh = m2;
        }
        __syncthreads();
        float e = expf(v - mx_sh);
        p_lds[tid] = e;
        float sv = e;
        #pragma unroll
        for (int o = 32; o; o >>= 1) sv += __shfl_xor(sv, o);
        if (lane == 0) red[wid] = sv;
        __syncthreads();
        if (tid == 0) {
            float s2 = 0.f;
            for (int w = 0; w < 8; ++w) s2 += red[w];
            sum_sh = s2;
        }
        __syncthreads();
        if (wid < 4) {
            const float4* mr = m4 + wid * 128;
            float acc = 0.f;
            #pragma unroll
            for (int i = 0; i < 2; ++i) {
                float4 mv4 = mr[lane + 64 * i];
                float4 pv4 = ((const float4*)p_lds)[lane + 64 * i];
                acc += mv4.x*pv4.x + mv4.y*pv4.y + mv4.z*pv4.z + mv4.w*pv4.w;
            }
            #pragma unroll
            for (int o = 32; o; o >>= 1) acc += __shfl_xor(acc, o);
            if (lane == 0) {
                float xv = ce + acc / sum_sh;
                x_buf[j0 + wid] = fmaxf(xv, 0.f);
            }
        }
        grid_barrier(bar, 3 * t + 2);
        // -------- phase C: gi = W_ih@x + b_ih ; gates ; h2 -----------------
        if (tid < 256) ((float4*)x_lds)[tid] = ((const float4*)x_buf)[tid];
        __syncthreads();
        for (int rr = wid; rr < 12; rr += 8) {
            const float4* wrow = wih4 + rr * 256;
            float acc = 0.f;
            #pragma unroll
            for (int i = 0; i < 4; ++i) {
                float4 wv = wrow[lane + 64 * i];
                float4 xv = ((const float4*)x_lds)[lane + 64 * i];
                acc += wv.x*xv.x + wv.y*xv.y + wv.z*xv.z + wv.w*xv.w;
            }
            #pragma unroll
            for (int o = 32; o; o >>= 1) acc += __shfl_xor(acc, o);
            if (lane == 0) gi_lds[rr] = acc + bih_lds[rr];
        }
        __syncthreads();
        if (tid < 4) {
            float r = sigmoidf_(gi_lds[tid] + gh_lds[tid]);
            float z = sigmoidf_(gi_lds[4 + tid] + gh_lds[4 + tid]);
            float n = tanhf(gi_lds[8 + tid] + r * gh_lds[8 + tid]);
            float hp = h_lds[j0 + tid];
            H2[(size_t)t * 1024 + j0 + tid] = (1.f - z) * n + z * hp;
        }
        if (t < T - 1) grid_barrier(bar, 3 * t + 3);
    }
}

// ------------------- output GEMM + fused LSE partials ----------------------
// grid (250, 4), block 256; tile 128(cols) x 128(rows), thread 8x8.
__global__ __launch_bounds__(256) void out_gemm_lse(
    const float* __restrict__ H2, const float* __restrict__ outW,
    const float* __restrict__ outB, const int* __restrict__ tgt,
    float* __restrict__ lsep, float* __restrict__ tgtlog)
{
    __shared__ float A_lds[32][128];
    __shared__ float B_lds[32][128];
    const int tid = threadIdx.x;
    const int tx = tid & 15, ty = tid >> 4;
    const int c0 = blockIdx.x * 128, r0 = blockIdx.y * 128;
    float acc[8][8] = {};

    for (int k0 = 0; k0 < 1024; k0 += 32) {
        #pragma unroll
        for (int q = 0; q < 4; ++q) {
            int f4 = tid + q * 256;          // 0..1023
            int row = f4 >> 3, c4 = f4 & 7;
            float4 a = *(const float4*)(H2 + (size_t)(r0 + row) * 1024 + k0 + c4 * 4);
            A_lds[c4*4+0][row] = a.x; A_lds[c4*4+1][row] = a.y;
            A_lds[c4*4+2][row] = a.z; A_lds[c4*4+3][row] = a.w;
            float4 b = *(const float4*)(outW + (size_t)(c0 + row) * 1024 + k0 + c4 * 4);
            B_lds[c4*4+0][row] = b.x; B_lds[c4*4+1][row] = b.y;
            B_lds[c4*4+2][row] = b.z; B_lds[c4*4+3][row] = b.w;
        }
        __syncthreads();
        #pragma unroll
        for (int kk = 0; kk < 32; ++kk) {
            float4 a0 = *(const float4*)&A_lds[kk][ty * 8];
            float4 a1 = *(const float4*)&A_lds[kk][ty * 8 + 4];
            float4 b0 = *(const float4*)&B_lds[kk][tx * 8];
            float4 b1 = *(const float4*)&B_lds[kk][tx * 8 + 4];
            float av[8] = {a0.x,a0.y,a0.z,a0.w,a1.x,a1.y,a1.z,a1.w};
            float bv[8] = {b0.x,b0.y,b0.z,b0.w,b1.x,b1.y,b1.z,b1.w};
            #pragma unroll
            for (int i = 0; i < 8; ++i)
                #pragma unroll
                for (int j = 0; j < 8; ++j)
                    acc[i][j] = fmaf(av[i], bv[j], acc[i][j]);
        }
        __syncthreads();
    }
    float bj[8];
    #pragma unroll
    for (int j = 0; j < 8; ++j) bj[j] = outB[c0 + tx * 8 + j];

    const int bx = blockIdx.x;
    #pragma unroll
    for (int i = 0; i < 8; ++i) {
        int t = r0 + ty * 8 + i;
        float rowv[8];
        float vmax = -INFINITY;
        #pragma unroll
        for (int j = 0; j < 8; ++j) {
            rowv[j] = acc[i][j] + bj[j];
            vmax = fmaxf(vmax, rowv[j]);
        }
        float ssum = 0.f;
        #pragma unroll
        for (int j = 0; j < 8; ++j) ssum += expf(rowv[j] - vmax);
        #pragma unroll
        for (int o = 1; o < 16; o <<= 1) {
            float om = __shfl_xor(vmax, o);
            float os = __shfl_xor(ssum, o);
            float nm = fmaxf(vmax, om);
            ssum = ssum * expf(vmax - nm) + os * expf(om - nm);
            vmax = nm;
        }
        if (tx == 0)
            *(float2*)&lsep[((size_t)t * 250 + bx) * 2] = make_float2(vmax, ssum);
        int tv = tgt[t];
        if (tv >= c0 && tv < c0 + 128) {
            int rel = tv - c0;
            if ((rel >> 3) == tx) tgtlog[t] = rowv[rel & 7];
        }
    }
}

// ------------------------- final combine -----------------------------------
__global__ __launch_bounds__(512) void lse_combine(
    const float* __restrict__ lsep, const float* __restrict__ tgtlog,
    float* __restrict__ out)
{
    const int t = threadIdx.x;     // 0..511
    float m = -INFINITY, s = 0.f;
    for (int cb = 0; cb < 250; ++cb) {
        float2 p = *(const float2*)&lsep[((size_t)t * 250 + cb) * 2];
        float nm = fmaxf(m, p.x);
        s = s * expf(m - nm) + p.y * expf(p.x - nm);
        m = nm;
    }
    float nll = (m + logf(s)) - tgtlog[t];
    __shared__ float red[8];
    float v = nll;
    #pragma unroll
    for (int o = 32; o; o >>= 1) v += __shfl_xor(v, o);
    if ((t & 63) == 0) red[t >> 6] = v;
    __syncthreads();
    if (t == 0) {
        float sum = 0.f;
        for (int w = 0; w < 8; ++w) sum += red[w];
        out[0] = sum / 512.f;
    }
}

// ---------------------------------------------------------------------------
extern "C" void kernel_launch(void* const* d_in, const int* in_sizes, int n_in,
                              void* d_out, int out_size, void* d_ws, size_t ws_size,
                              hipStream_t stream) {
    const int*   input   = (const int*)d_in[0];
    const int*   target  = (const int*)d_in[1];
    const float* enc_emb = (const float*)d_in[2];
    const float* eWih    = (const float*)d_in[3];
    const float* eWhh    = (const float*)d_in[4];
    const float* ebih    = (const float*)d_in[5];
    const float* ebhh    = (const float*)d_in[6];
    const float* dec_emb = (const float*)d_in[7];
    const float* attnW   = (const float*)d_in[8];
    const float* attnB   = (const float*)d_in[9];
    const float* combW   = (const float*)d_in[10];
    const float* combB   = (const float*)d_in[11];
    const float* dWih    = (const float*)d_in[12];
    const float* dWhh    = (const float*)d_in[13];
    const float* dbih    = (const float*)d_in[14];
    const float* dbhh    = (const float*)d_in[15];
    const float* outW    = (const float*)d_in[16];
    const float* outB    = (const float*)d_in[17];
    float* out = (float*)d_out;

    float* wsf = (float*)d_ws;
    unsigned* barE = (unsigned*)d_ws;                         // bytes [0,4096)
    unsigned* barD = (unsigned*)((char*)d_ws + 4096);         // bytes [4096,8192)
    const float* zero_row = (const float*)((char*)d_ws + 8192); // [8192,12288)
    float* enc_gi   = wsf + 4096;      // [512][3072]
    float* enc_outs = wsf + 1576960;   // [512][1024]
    float* attn_e   = wsf + 2101248;   // [512][512]
    float* comb_e   = wsf + 2363392;   // [512][1024]
    float* Mws      = wsf + 2887680;   // [1024][512]
    float* H2       = wsf + 3411968;   // [512][1024]
    float* s_buf    = wsf + 3936256;   // [512]
    float* x_buf    = wsf + 3936768;   // [1024]
    float* lsep     = wsf + 3937792;   // [512][250][2]
    float* tgtlog   = wsf + 4193792;   // [512]

    hipMemsetAsync(d_ws, 0, 12288, stream);   // barriers + zero row

    // K1: token-indexed precomputes
    gemm_tn<<<dim3(48, 8), 256, 0, stream>>>(enc_emb, 1024, 0, input, 1,
        eWih, 1024, 0, ebih, enc_gi, 3072, 1024);
    gemm_tn<<<dim3(8, 8), 256, 0, stream>>>(dec_emb, 1024, 0, target, 2,
        attnW, 2048, 0, attnB, attn_e, 512, 1024);
    gemm_tn<<<dim3(16, 8), 256, 0, stream>>>(dec_emb, 1024, 0, target, 2,
        combW, 2048, 0, combB, comb_e, 1024, 1024);

    // K2: encoder recurrence
    enc_seq<<<256, 512, 0, stream>>>(eWhh, ebhh, enc_gi, enc_outs, zero_row, barE);

    // K3: M = comb_W[:, H:] @ enc_outs^T
    gemm_tn<<<dim3(8, 16), 256, 0, stream>>>(combW, 2048, 1024, nullptr, 0,
        enc_outs, 1024, 0, nullptr, Mws, 512, 1024);

    // K4: decoder recurrence
    dec_seq<<<256, 512, 0, stream>>>(dWih, dWhh, dbih, dbhh, attnW,
        attn_e, comb_e, Mws, enc_outs, H2, s_buf, x_buf, barD);

    // K5: logits GEMM + fused LSE partials
    out_gemm_lse<<<dim3(250, 4), 256, 0, stream>>>(H2, outW, outB, target,
        lsep, tgtlog);

    // K6: combine -> scalar
    lse_combine<<<1, 512, 0, stream>>>(lsep, tgtlog, out);
}

// Round 2
// 7673.055 us; speedup vs baseline: 2.6150x; 2.6150x over previous
//
#include <hip/hip_runtime.h>
#include <math.h>

// ---------------------------------------------------------------------------
// Seq2seq (GRU enc + attn GRU dec, teacher forcing) -> mean NLL scalar.
//   K1a: enc_gi[512][3072] = enc_emb[input] @ enc_W_ih^T + b_ih      (GEMM)
//   K1b: attn_e[512][512]  = dec_emb[dec_in] @ attn_W[:, :H]^T + attn_b
//   K1c: comb_e[512][1024] = dec_emb[dec_in] @ comb_W[:, :H]^T + comb_b
//   K2 : persistent encoder recurrence (512 steps, 1 exchange/step)
//   K3 : M[1024][512] = comb_W[:, H:] @ enc_outs^T                   (GEMM)
//   K4 : persistent decoder recurrence (512 steps, 3 exchanges/step)
//   K5 : logits GEMM [512,32000] + fused per-row (max, sumexp) partials
//   K6 : combine partials -> lse -> mean NLL -> d_out[0]
// Cross-block exchange: relaxed agent-scope atomics only (sc1 write-through
// to coherence point + sc1 loads). NO acq/rel fences -> no buffer_wbl2 /
// buffer_inv per barrier (that was 9.3us/barrier in round 1).
// ---------------------------------------------------------------------------

#define H 1024
#define T 512
#define V 32000

typedef unsigned long long u64;

// -------- agent-scope mailbox primitives (no cache maintenance) ------------
__device__ __forceinline__ void st_agent_f32(float* p, float v) {
    __hip_atomic_store(p, v, __ATOMIC_RELAXED, __HIP_MEMORY_SCOPE_AGENT);
}
__device__ __forceinline__ float2 ld_agent_f2(const float* p) {
    u64 u = __hip_atomic_load((const u64*)p, __ATOMIC_RELAXED,
                              __HIP_MEMORY_SCOPE_AGENT);
    float2 t;
    __builtin_memcpy(&t, &u, 8);
    return t;
}

// -------- grid barrier: 8 spread group counters, relaxed everywhere --------
// cnts: 8 counters at uint stride 64 (256B apart). target = 256 * phase_no.
// __syncthreads() drains each wave's vmcnt -> all sc1 data stores are ack'd
// at the coherence point before any arrive-add is issued.
__device__ __forceinline__ void grid_barrier(unsigned* cnts, unsigned target) {
    __syncthreads();
    if (threadIdx.x == 0) {
        __hip_atomic_fetch_add(cnts + ((blockIdx.x & 7) * 64), 1u,
                               __ATOMIC_RELAXED, __HIP_MEMORY_SCOPE_AGENT);
        unsigned sum;
        do {
            sum = 0;
            #pragma unroll
            for (int g = 0; g < 8; ++g)
                sum += __hip_atomic_load(cnts + g * 64, __ATOMIC_RELAXED,
                                         __HIP_MEMORY_SCOPE_AGENT);
        } while (sum < target);
        asm volatile("" ::: "memory");
    }
    __syncthreads();
}

__device__ __forceinline__ float sigmoidf_(float x) { return 1.f / (1.f + expf(-x)); }

// ------------------------- generic tiled GEMM ------------------------------
// C[t,n] = sum_k Xrow(t)[k] * Wrow(n)[k] (+ bias[n])
// Xrow(t): gmode 0 -> X + t*xs + xo ; 1 -> X + idx[t]*xs + xo ;
//          2 -> X + ((t==0)?0:idx[t-1])*xs + xo   (teacher-forced dec input)
__global__ __launch_bounds__(256) void gemm_tn(
    const float* __restrict__ X, int xs, int xo,
    const int* __restrict__ gidx, int gmode,
    const float* __restrict__ W, int wsd, int wo,
    const float* __restrict__ bias,
    float* __restrict__ C, int cs, int K)
{
    __shared__ float A_lds[32][64];
    __shared__ float B_lds[32][64];
    const int tid = threadIdx.x;
    const int tx = tid & 15, ty = tid >> 4;
    const int n0 = blockIdx.x * 64, t0 = blockIdx.y * 64;
    float acc[4][4] = {};

    for (int k0 = 0; k0 < K; k0 += 32) {
        #pragma unroll
        for (int q = 0; q < 2; ++q) {
            int f4 = tid + q * 256;          // 0..511
            int row = f4 >> 3, c4 = f4 & 7;
            int trow = t0 + row;
            const float* xr;
            if (gmode == 0)      xr = X + (size_t)trow * xs + xo;
            else if (gmode == 1) xr = X + (size_t)gidx[trow] * xs + xo;
            else { int tok = (trow == 0) ? 0 : gidx[trow - 1];
                   xr = X + (size_t)tok * xs + xo; }
            float4 a = *(const float4*)(xr + k0 + c4 * 4);
            A_lds[c4*4+0][row] = a.x; A_lds[c4*4+1][row] = a.y;
            A_lds[c4*4+2][row] = a.z; A_lds[c4*4+3][row] = a.w;
            const float* wr = W + (size_t)(n0 + row) * wsd + wo;
            float4 b = *(const float4*)(wr + k0 + c4 * 4);
            B_lds[c4*4+0][row] = b.x; B_lds[c4*4+1][row] = b.y;
            B_lds[c4*4+2][row] = b.z; B_lds[c4*4+3][row] = b.w;
        }
        __syncthreads();
        #pragma unroll
        for (int kk = 0; kk < 32; ++kk) {
            float4 a = *(const float4*)&A_lds[kk][ty * 4];
            float4 b = *(const float4*)&B_lds[kk][tx * 4];
            float av[4] = {a.x, a.y, a.z, a.w};
            float bv[4] = {b.x, b.y, b.z, b.w};
            #pragma unroll
            for (int i = 0; i < 4; ++i)
                #pragma unroll
                for (int j = 0; j < 4; ++j)
                    acc[i][j] = fmaf(av[i], bv[j], acc[i][j]);
        }
        __syncthreads();
    }
    float bj[4];
    #pragma unroll
    for (int j = 0; j < 4; ++j) bj[j] = bias ? bias[n0 + tx * 4 + j] : 0.f;
    #pragma unroll
    for (int i = 0; i < 4; ++i)
        #pragma unroll
        for (int j = 0; j < 4; ++j)
            C[(size_t)(t0 + ty * 4 + i) * cs + n0 + tx * 4 + j] = acc[i][j] + bj[j];
}

// ------------------------- encoder recurrence ------------------------------
// 256 blocks x 512 threads; block b owns h indices [4b, 4b+4).
// LDS-resident W_hh rows (12 x 1024). 1 mailbox exchange per step.
__global__ __launch_bounds__(512) void enc_seq(
    const float* __restrict__ Whh, const float* __restrict__ bhh,
    const float* __restrict__ gi,          // enc_gi [512][3072]
    float* __restrict__ enc_outs,          // [512][1024]
    unsigned* __restrict__ bar)
{
    __shared__ float4 w4[12 * 256];
    __shared__ float h_lds[1024];
    __shared__ float gh_lds[12];
    __shared__ float bias_lds[12];
    const int tid = threadIdx.x, bid = blockIdx.x;
    const int j0 = bid * 4;
    for (int i = tid; i < 12 * 256; i += 512) {
        int r = i >> 8, c = i & 255;
        int grow = (r >> 2) * 1024 + j0 + (r & 3);
        w4[i] = *(const float4*)(Whh + (size_t)grow * 1024 + c * 4);
    }
    if (tid < 12) bias_lds[tid] = bhh[(tid >> 2) * 1024 + j0 + (tid & 3)];
    __syncthreads();

    const int wid = tid >> 6, lane = tid & 63;
    for (int t = 0; t < T; ++t) {
        if (t == 0) {
            if (tid < 256) ((float4*)h_lds)[tid] = make_float4(0.f, 0.f, 0.f, 0.f);
        } else {
            float2 hv = ld_agent_f2(enc_outs + (size_t)(t - 1) * 1024 + tid * 2);
            ((float2*)h_lds)[tid] = hv;
        }
        // prefetch gi for the gate combine (overlaps with dots)
        float gir = 0.f, giz = 0.f, gin = 0.f;
        if (tid < 4) {
            const float* gr = gi + (size_t)t * 3072 + j0 + tid;
            gir = gr[0]; giz = gr[1024]; gin = gr[2048];
        }
        __syncthreads();
        for (int rr = wid; rr < 12; rr += 8) {
            const float4* wrow = w4 + rr * 256;
            float acc = 0.f;
            #pragma unroll
            for (int i = 0; i < 4; ++i) {
                float4 wv = wrow[lane + 64 * i];
                float4 hv = ((const float4*)h_lds)[lane + 64 * i];
                acc += wv.x*hv.x + wv.y*hv.y + wv.z*hv.z + wv.w*hv.w;
            }
            #pragma unroll
            for (int o = 32; o; o >>= 1) acc += __shfl_xor(acc, o);
            if (lane == 0) gh_lds[rr] = acc + bias_lds[rr];
        }
        __syncthreads();
        if (tid < 4) {
            float r = sigmoidf_(gir + gh_lds[tid]);
            float z = sigmoidf_(giz + gh_lds[4 + tid]);
            float n = tanhf(gin + r * gh_lds[8 + tid]);
            float hp = h_lds[j0 + tid];
            st_agent_f32(enc_outs + (size_t)t * 1024 + j0 + tid,
                         (1.f - z) * n + z * hp);
        }
        if (t < T - 1) grid_barrier(bar, 256u * (unsigned)(t + 1));
    }
}

// ------------------------- decoder recurrence ------------------------------
// 256 blocks x 512 threads; block b owns h indices [4b,4b+4) and s indices
// [2b,2b+2). LDS-resident: dec_W_ih, dec_W_hh (12 rows each), attn_W h-half
// (2 rows), M (4 rows). 3 mailbox exchanges per step.
__global__ __launch_bounds__(512) void dec_seq(
    const float* __restrict__ Wih, const float* __restrict__ Whh,
    const float* __restrict__ bih, const float* __restrict__ bhh,
    const float* __restrict__ attnW,   // [512][2048]
    const float* __restrict__ attn_e,  // [512][512]
    const float* __restrict__ comb_e,  // [512][1024]
    const float* __restrict__ M,       // [1024][512]
    const float* __restrict__ enc_outs,
    float* __restrict__ H2,            // [512][1024]
    float* __restrict__ s_buf, float* __restrict__ x_buf,
    unsigned* __restrict__ bar)
{
    __shared__ float4 wih4[12 * 256];
    __shared__ float4 whh4[12 * 256];
    __shared__ float4 aw4[2 * 256];
    __shared__ float4 m4[4 * 128];
    __shared__ float h_lds[1024];
    __shared__ float x_lds[1024];
    __shared__ float p_lds[512];
    __shared__ float gh_lds[12], gi_lds[12];
    __shared__ float bih_lds[12], bhh_lds[12];
    __shared__ float red[8];
    __shared__ float mx_sh, sum_sh;

    const int tid = threadIdx.x, bid = blockIdx.x;
    const int j0 = bid * 4, l0 = bid * 2;
    for (int i = tid; i < 12 * 256; i += 512) {
        int r = i >> 8, c = i & 255;
        int grow = (r >> 2) * 1024 + j0 + (r & 3);
        wih4[i] = *(const float4*)(Wih + (size_t)grow * 1024 + c * 4);
        whh4[i] = *(const float4*)(Whh + (size_t)grow * 1024 + c * 4);
    }
    for (int i = tid; i < 2 * 256; i += 512) {
        int r = i >> 8, c = i & 255;
        aw4[i] = *(const float4*)(attnW + (size_t)(l0 + r) * 2048 + 1024 + c * 4);
    }
    for (int i = tid; i < 4 * 128; i += 512) {
        int r = i >> 7, c = i & 127;
        m4[i] = *(const float4*)(M + (size_t)(j0 + r) * 512 + c * 4);
    }
    if (tid < 12) {
        int grow = (tid >> 2) * 1024 + j0 + (tid & 3);
        bih_lds[tid] = bih[grow]; bhh_lds[tid] = bhh[grow];
    }
    __syncthreads();

    const int wid = tid >> 6, lane = tid & 63;
    for (int t = 0; t < T; ++t) {
        // -------- phase A: s = attn_e + A_h@h ; gh = W_hh@h + b_hh --------
        const float* hsrc = (t == 0) ? (enc_outs + (size_t)(T - 1) * 1024)
                                     : (H2 + (size_t)(t - 1) * 1024);
        {
            float2 hv = ld_agent_f2(hsrc + tid * 2);
            ((float2*)h_lds)[tid] = hv;
        }
        float ae = 0.f;
        if ((wid == 4 || wid == 5) && lane == 0)
            ae = attn_e[(size_t)t * 512 + l0 + (wid - 4)];
        __syncthreads();
        for (int rr = wid; rr < 14; rr += 8) {
            const float4* wrow = (rr < 12) ? (whh4 + rr * 256) : (aw4 + (rr - 12) * 256);
            float acc = 0.f;
            #pragma unroll
            for (int i = 0; i < 4; ++i) {
                float4 wv = wrow[lane + 64 * i];
                float4 hv = ((const float4*)h_lds)[lane + 64 * i];
                acc += wv.x*hv.x + wv.y*hv.y + wv.z*hv.z + wv.w*hv.w;
            }
            #pragma unroll
            for (int o = 32; o; o >>= 1) acc += __shfl_xor(acc, o);
            if (lane == 0) {
                if (rr < 12) gh_lds[rr] = acc + bhh_lds[rr];
                else         st_agent_f32(s_buf + l0 + (rr - 12), acc + ae);
            }
        }
        grid_barrier(bar, 256u * (unsigned)(3 * t + 1));
        // -------- phase B: softmax(s) ; x = relu(comb_e + M@aw) -----------
        if (tid < 256) {
            float2 sv2 = ld_agent_f2(s_buf + tid * 2);
            ((float2*)p_lds)[tid] = sv2;
        }
        float ce = 0.f;
        if (wid < 4 && lane == 0) ce = comb_e[(size_t)t * 1024 + j0 + wid];
        __syncthreads();
        float v = p_lds[tid];
        float mv = v;
        #pragma unroll
        for (int o = 32; o; o >>= 1) mv = fmaxf(mv, __shfl_xor(mv, o));
        if (lane == 0) red[wid] = mv;
        __syncthreads();
        if (tid == 0) {
            float m2 = red[0];
            for (int w = 1; w < 8; ++w) m2 = fmaxf(m2, red[w]);
            mx_sh = m2;
        }
        __syncthreads();
        float e = expf(v - mx_sh);
        p_lds[tid] = e;
        float sv = e;
        #pragma unroll
        for (int o = 32; o; o >>= 1) sv += __shfl_xor(sv, o);
        if (lane == 0) red[wid] = sv;
        __syncthreads();
        if (tid == 0) {
            float s2 = 0.f;
            for (int w = 0; w < 8; ++w) s2 += red[w];
            sum_sh = s2;
        }
        __syncthreads();
        if (wid < 4) {
            const float4* mr = m4 + wid * 128;
            float acc = 0.f;
            #pragma unroll
            for (int i = 0; i < 2; ++i) {
                float4 mv4 = mr[lane + 64 * i];
                float4 pv4 = ((const float4*)p_lds)[lane + 64 * i];
                acc += mv4.x*pv4.x + mv4.y*pv4.y + mv4.z*pv4.z + mv4.w*pv4.w;
            }
            #pragma unroll
            for (int o = 32; o; o >>= 1) acc += __shfl_xor(acc, o);
            if (lane == 0) {
                float xv = ce + acc / sum_sh;
                st_agent_f32(x_buf + j0 + wid, fmaxf(xv, 0.f));
            }
        }
        grid_barrier(bar, 256u * (unsigned)(3 * t + 2));
        // -------- phase C: gi = W_ih@x + b_ih ; gates ; h2 -----------------
        {
            float2 xv2 = ld_agent_f2(x_buf + tid * 2);
            ((float2*)x_lds)[tid] = xv2;
        }
        __syncthreads();
        for (int rr = wid; rr < 12; rr += 8) {
            const float4* wrow = wih4 + rr * 256;
            float acc = 0.f;
            #pragma unroll
            for (int i = 0; i < 4; ++i) {
                float4 wv = wrow[lane + 64 * i];
                float4 xv = ((const float4*)x_lds)[lane + 64 * i];
                acc += wv.x*xv.x + wv.y*xv.y + wv.z*xv.z + wv.w*xv.w;
            }
            #pragma unroll
            for (int o = 32; o; o >>= 1) acc += __shfl_xor(acc, o);
            if (lane == 0) gi_lds[rr] = acc + bih_lds[rr];
        }
        __syncthreads();
        if (tid < 4) {
            float r = sigmoidf_(gi_lds[tid] + gh_lds[tid]);
            float z = sigmoidf_(gi_lds[4 + tid] + gh_lds[4 + tid]);
            float n = tanhf(gi_lds[8 + tid] + r * gh_lds[8 + tid]);
            float hp = h_lds[j0 + tid];
            st_agent_f32(H2 + (size_t)t * 1024 + j0 + tid,
                         (1.f - z) * n + z * hp);
        }
        if (t < T - 1) grid_barrier(bar, 256u * (unsigned)(3 * t + 3));
    }
}

// ------------------- output GEMM + fused LSE partials ----------------------
// grid (250, 4), block 256; tile 128(cols) x 128(rows), thread 8x8.
__global__ __launch_bounds__(256) void out_gemm_lse(
    const float* __restrict__ H2, const float* __restrict__ outW,
    const float* __restrict__ outB, const int* __restrict__ tgt,
    float* __restrict__ lsep, float* __restrict__ tgtlog)
{
    __shared__ float A_lds[32][128];
    __shared__ float B_lds[32][128];
    const int tid = threadIdx.x;
    const int tx = tid & 15, ty = tid >> 4;
    const int c0 = blockIdx.x * 128, r0 = blockIdx.y * 128;
    float acc[8][8] = {};

    for (int k0 = 0; k0 < 1024; k0 += 32) {
        #pragma unroll
        for (int q = 0; q < 4; ++q) {
            int f4 = tid + q * 256;          // 0..1023
            int row = f4 >> 3, c4 = f4 & 7;
            float4 a = *(const float4*)(H2 + (size_t)(r0 + row) * 1024 + k0 + c4 * 4);
            A_lds[c4*4+0][row] = a.x; A_lds[c4*4+1][row] = a.y;
            A_lds[c4*4+2][row] = a.z; A_lds[c4*4+3][row] = a.w;
            float4 b = *(const float4*)(outW + (size_t)(c0 + row) * 1024 + k0 + c4 * 4);
            B_lds[c4*4+0][row] = b.x; B_lds[c4*4+1][row] = b.y;
            B_lds[c4*4+2][row] = b.z; B_lds[c4*4+3][row] = b.w;
        }
        __syncthreads();
        #pragma unroll
        for (int kk = 0; kk < 32; ++kk) {
            float4 a0 = *(const float4*)&A_lds[kk][ty * 8];
            float4 a1 = *(const float4*)&A_lds[kk][ty * 8 + 4];
            float4 b0 = *(const float4*)&B_lds[kk][tx * 8];
            float4 b1 = *(const float4*)&B_lds[kk][tx * 8 + 4];
            float av[8] = {a0.x,a0.y,a0.z,a0.w,a1.x,a1.y,a1.z,a1.w};
            float bv[8] = {b0.x,b0.y,b0.z,b0.w,b1.x,b1.y,b1.z,b1.w};
            #pragma unroll
            for (int i = 0; i < 8; ++i)
                #pragma unroll
                for (int j = 0; j < 8; ++j)
                    acc[i][j] = fmaf(av[i], bv[j], acc[i][j]);
        }
        __syncthreads();
    }
    float bj[8];
    #pragma unroll
    for (int j = 0; j < 8; ++j) bj[j] = outB[c0 + tx * 8 + j];

    const int bx = blockIdx.x;
    #pragma unroll
    for (int i = 0; i < 8; ++i) {
        int t = r0 + ty * 8 + i;
        float rowv[8];
        float vmax = -INFINITY;
        #pragma unroll
        for (int j = 0; j < 8; ++j) {
            rowv[j] = acc[i][j] + bj[j];
            vmax = fmaxf(vmax, rowv[j]);
        }
        float ssum = 0.f;
        #pragma unroll
        for (int j = 0; j < 8; ++j) ssum += expf(rowv[j] - vmax);
        #pragma unroll
        for (int o = 1; o < 16; o <<= 1) {
            float om = __shfl_xor(vmax, o);
            float os = __shfl_xor(ssum, o);
            float nm = fmaxf(vmax, om);
            ssum = ssum * expf(vmax - nm) + os * expf(om - nm);
            vmax = nm;
        }
        if (tx == 0)
            *(float2*)&lsep[((size_t)t * 250 + bx) * 2] = make_float2(vmax, ssum);
        int tv = tgt[t];
        if (tv >= c0 && tv < c0 + 128) {
            int rel = tv - c0;
            if ((rel >> 3) == tx) tgtlog[t] = rowv[rel & 7];
        }
    }
}

// ------------------------- final combine -----------------------------------
__global__ __launch_bounds__(512) void lse_combine(
    const float* __restrict__ lsep, const float* __restrict__ tgtlog,
    float* __restrict__ out)
{
    const int t = threadIdx.x;     // 0..511
    float m = -INFINITY, s = 0.f;
    for (int cb = 0; cb < 250; ++cb) {
        float2 p = *(const float2*)&lsep[((size_t)t * 250 + cb) * 2];
        float nm = fmaxf(m, p.x);
        s = s * expf(m - nm) + p.y * expf(p.x - nm);
        m = nm;
    }
    float nll = (m + logf(s)) - tgtlog[t];
    __shared__ float red[8];
    float v = nll;
    #pragma unroll
    for (int o = 32; o; o >>= 1) v += __shfl_xor(v, o);
    if ((t & 63) == 0) red[t >> 6] = v;
    __syncthreads();
    if (t == 0) {
        float sum = 0.f;
        for (int w = 0; w < 8; ++w) sum += red[w];
        out[0] = sum / 512.f;
    }
}

// ---------------------------------------------------------------------------
extern "C" void kernel_launch(void* const* d_in, const int* in_sizes, int n_in,
                              void* d_out, int out_size, void* d_ws, size_t ws_size,
                              hipStream_t stream) {
    const int*   input   = (const int*)d_in[0];
    const int*   target  = (const int*)d_in[1];
    const float* enc_emb = (const float*)d_in[2];
    const float* eWih    = (const float*)d_in[3];
    const float* eWhh    = (const float*)d_in[4];
    const float* ebih    = (const float*)d_in[5];
    const float* ebhh    = (const float*)d_in[6];
    const float* dec_emb = (const float*)d_in[7];
    const float* attnW   = (const float*)d_in[8];
    const float* attnB   = (const float*)d_in[9];
    const float* combW   = (const float*)d_in[10];
    const float* combB   = (const float*)d_in[11];
    const float* dWih    = (const float*)d_in[12];
    const float* dWhh    = (const float*)d_in[13];
    const float* dbih    = (const float*)d_in[14];
    const float* dbhh    = (const float*)d_in[15];
    const float* outW    = (const float*)d_in[16];
    const float* outB    = (const float*)d_in[17];
    float* out = (float*)d_out;

    float* wsf = (float*)d_ws;
    unsigned* barE = (unsigned*)d_ws;                         // bytes [0,4096)
    unsigned* barD = (unsigned*)((char*)d_ws + 4096);         // bytes [4096,8192)
    float* enc_gi   = wsf + 4096;      // [512][3072]
    float* enc_outs = wsf + 1576960;   // [512][1024]
    float* attn_e   = wsf + 2101248;   // [512][512]
    float* comb_e   = wsf + 2363392;   // [512][1024]
    float* Mws      = wsf + 2887680;   // [1024][512]
    float* H2       = wsf + 3411968;   // [512][1024]
    float* s_buf    = wsf + 3936256;   // [512]
    float* x_buf    = wsf + 3936768;   // [1024]
    float* lsep     = wsf + 3937792;   // [512][250][2]
    float* tgtlog   = wsf + 4193792;   // [512]

    hipMemsetAsync(d_ws, 0, 12288, stream);   // barrier counters

    // K1: token-indexed precomputes
    gemm_tn<<<dim3(48, 8), 256, 0, stream>>>(enc_emb, 1024, 0, input, 1,
        eWih, 1024, 0, ebih, enc_gi, 3072, 1024);
    gemm_tn<<<dim3(8, 8), 256, 0, stream>>>(dec_emb, 1024, 0, target, 2,
        attnW, 2048, 0, attnB, attn_e, 512, 1024);
    gemm_tn<<<dim3(16, 8), 256, 0, stream>>>(dec_emb, 1024, 0, target, 2,
        combW, 2048, 0, combB, comb_e, 1024, 1024);

    // K2: encoder recurrence
    enc_seq<<<256, 512, 0, stream>>>(eWhh, ebhh, enc_gi, enc_outs, barE);

    // K3: M = comb_W[:, H:] @ enc_outs^T
    gemm_tn<<<dim3(8, 16), 256, 0, stream>>>(combW, 2048, 1024, nullptr, 0,
        enc_outs, 1024, 0, nullptr, Mws, 512, 1024);

    // K4: decoder recurrence
    dec_seq<<<256, 512, 0, stream>>>(dWih, dWhh, dbih, dbhh, attnW,
        attn_e, comb_e, Mws, enc_outs, H2, s_buf, x_buf, barD);

    // K5: logits GEMM + fused LSE partials
    out_gemm_lse<<<dim3(250, 4), 256, 0, stream>>>(H2, outW, outB, target,
        lsep, tgtlog);

    // K6: combine -> scalar
    lse_combine<<<1, 512, 0, stream>>>(lsep, tgtlog, out);
}

// Round 3
// 7380.146 us; speedup vs baseline: 2.7188x; 1.0397x over previous
//
#include <hip/hip_runtime.h>
#include <math.h>

// ---------------------------------------------------------------------------
// Seq2seq (GRU enc + attn GRU dec, teacher forcing) -> mean NLL scalar.
//   K1a: enc_gi[512][3072] = enc_emb[input] @ enc_W_ih^T + b_ih      (GEMM)
//   K1b: attn_e[512][512]  = dec_emb[dec_in] @ attn_W[:, :H]^T + attn_b
//   K1c: comb_e[512][1024] = dec_emb[dec_in] @ comb_W[:, :H]^T + comb_b
//   K2 : persistent encoder recurrence (512 steps, 1 exchange/step)
//   K3 : M[1024][512] = comb_W[:, H:] @ enc_outs^T                   (GEMM)
//   K4 : persistent decoder recurrence (512 steps, 3 exchanges/step)
//   K5 : logits GEMM [512,32000] + fused per-row (max, sumexp) partials
//   K6 : combine partials -> lse -> mean NLL -> d_out[0]
//
// Exchange protocol (atomic-free): producers write data with relaxed
// agent-scope stores (write-through to coherence point), drain vmcnt, then
// arrive by storing the phase number into a per-block slot (256 slots,
// 64B stride -> zero same-address serialization). Wave0 polls all 256
// slots in parallel (4 loads/lane, __all) -> detection = 1 IC round trip.
// Off-path compute (gh rows) overlaps the barrier wait in other waves.
// ---------------------------------------------------------------------------

#define H 1024
#define T 512
#define V 32000

typedef unsigned long long u64;

// -------- agent-scope mailbox primitives (no cache maintenance) ------------
__device__ __forceinline__ void st_agent_f32(float* p, float v) {
    __hip_atomic_store(p, v, __ATOMIC_RELAXED, __HIP_MEMORY_SCOPE_AGENT);
}
__device__ __forceinline__ float2 ld_agent_f2(const float* p) {
    u64 u = __hip_atomic_load((const u64*)p, __ATOMIC_RELAXED,
                              __HIP_MEMORY_SCOPE_AGENT);
    float2 t;
    __builtin_memcpy(&t, &u, 8);
    return t;
}
__device__ __forceinline__ void st_slot(unsigned* p, unsigned v) {
    __hip_atomic_store(p, v, __ATOMIC_RELAXED, __HIP_MEMORY_SCOPE_AGENT);
}
__device__ __forceinline__ unsigned ld_slot(const unsigned* p) {
    return __hip_atomic_load(p, __ATOMIC_RELAXED, __HIP_MEMORY_SCOPE_AGENT);
}

// wave0-only: spin until every block's slot >= val. 256 slots, stride 16 u32.
__device__ __forceinline__ void poll_slots(const unsigned* slots, unsigned val,
                                           int lane) {
    for (;;) {
        unsigned a = ld_slot(slots + (lane      ) * 16);
        unsigned b = ld_slot(slots + (lane +  64) * 16);
        unsigned c = ld_slot(slots + (lane + 128) * 16);
        unsigned d = ld_slot(slots + (lane + 192) * 16);
        int ok = (a >= val) & (b >= val) & (c >= val) & (d >= val);
        if (__all(ok)) break;
    }
}

__device__ __forceinline__ float sigmoidf_(float x) { return 1.f / (1.f + expf(-x)); }

// ------------------------- generic tiled GEMM ------------------------------
// C[t,n] = sum_k Xrow(t)[k] * Wrow(n)[k] (+ bias[n])
// Xrow(t): gmode 0 -> X + t*xs + xo ; 1 -> X + idx[t]*xs + xo ;
//          2 -> X + ((t==0)?0:idx[t-1])*xs + xo   (teacher-forced dec input)
__global__ __launch_bounds__(256) void gemm_tn(
    const float* __restrict__ X, int xs, int xo,
    const int* __restrict__ gidx, int gmode,
    const float* __restrict__ W, int wsd, int wo,
    const float* __restrict__ bias,
    float* __restrict__ C, int cs, int K)
{
    __shared__ float A_lds[32][64];
    __shared__ float B_lds[32][64];
    const int tid = threadIdx.x;
    const int tx = tid & 15, ty = tid >> 4;
    const int n0 = blockIdx.x * 64, t0 = blockIdx.y * 64;
    float acc[4][4] = {};

    for (int k0 = 0; k0 < K; k0 += 32) {
        #pragma unroll
        for (int q = 0; q < 2; ++q) {
            int f4 = tid + q * 256;          // 0..511
            int row = f4 >> 3, c4 = f4 & 7;
            int trow = t0 + row;
            const float* xr;
            if (gmode == 0)      xr = X + (size_t)trow * xs + xo;
            else if (gmode == 1) xr = X + (size_t)gidx[trow] * xs + xo;
            else { int tok = (trow == 0) ? 0 : gidx[trow - 1];
                   xr = X + (size_t)tok * xs + xo; }
            float4 a = *(const float4*)(xr + k0 + c4 * 4);
            A_lds[c4*4+0][row] = a.x; A_lds[c4*4+1][row] = a.y;
            A_lds[c4*4+2][row] = a.z; A_lds[c4*4+3][row] = a.w;
            const float* wr = W + (size_t)(n0 + row) * wsd + wo;
            float4 b = *(const float4*)(wr + k0 + c4 * 4);
            B_lds[c4*4+0][row] = b.x; B_lds[c4*4+1][row] = b.y;
            B_lds[c4*4+2][row] = b.z; B_lds[c4*4+3][row] = b.w;
        }
        __syncthreads();
        #pragma unroll
        for (int kk = 0; kk < 32; ++kk) {
            float4 a = *(const float4*)&A_lds[kk][ty * 4];
            float4 b = *(const float4*)&B_lds[kk][tx * 4];
            float av[4] = {a.x, a.y, a.z, a.w};
            float bv[4] = {b.x, b.y, b.z, b.w};
            #pragma unroll
            for (int i = 0; i < 4; ++i)
                #pragma unroll
                for (int j = 0; j < 4; ++j)
                    acc[i][j] = fmaf(av[i], bv[j], acc[i][j]);
        }
        __syncthreads();
    }
    float bj[4];
    #pragma unroll
    for (int j = 0; j < 4; ++j) bj[j] = bias ? bias[n0 + tx * 4 + j] : 0.f;
    #pragma unroll
    for (int i = 0; i < 4; ++i)
        #pragma unroll
        for (int j = 0; j < 4; ++j)
            C[(size_t)(t0 + ty * 4 + i) * cs + n0 + tx * 4 + j] = acc[i][j] + bj[j];
}

// ------------------------- encoder recurrence ------------------------------
// 256 blocks x 512 threads; block b owns h indices [4b, 4b+4).
// LDS-resident W_hh rows (12 x 1024). 1 slot exchange per step.
__global__ __launch_bounds__(512) void enc_seq(
    const float* __restrict__ Whh, const float* __restrict__ bhh,
    const float* __restrict__ gi,          // enc_gi [512][3072]
    float* __restrict__ enc_outs,          // [512][1024]
    unsigned* __restrict__ slots)
{
    __shared__ float4 w4[12 * 256];
    __shared__ float h_lds[1024];
    __shared__ float gh_lds[12];
    __shared__ float bias_lds[12];
    const int tid = threadIdx.x, bid = blockIdx.x;
    const int j0 = bid * 4;
    for (int i = tid; i < 12 * 256; i += 512) {
        int r = i >> 8, c = i & 255;
        int grow = (r >> 2) * 1024 + j0 + (r & 3);
        w4[i] = *(const float4*)(Whh + (size_t)grow * 1024 + c * 4);
    }
    if (tid < 12) bias_lds[tid] = bhh[(tid >> 2) * 1024 + j0 + (tid & 3)];
    __syncthreads();

    const int wid = tid >> 6, lane = tid & 63;
    for (int t = 0; t < T; ++t) {
        if (t == 0) {
            if (tid < 256) ((float4*)h_lds)[tid] = make_float4(0.f, 0.f, 0.f, 0.f);
        } else {
            ((float2*)h_lds)[tid] =
                ld_agent_f2(enc_outs + (size_t)(t - 1) * 1024 + tid * 2);
        }
        float gir = 0.f, giz = 0.f, gin = 0.f;
        if (tid < 4) {
            const float* gr = gi + (size_t)t * 3072 + j0 + tid;
            gir = gr[0]; giz = gr[1024]; gin = gr[2048];
        }
        __syncthreads();
        for (int rr = wid; rr < 12; rr += 8) {
            const float4* wrow = w4 + rr * 256;
            float acc = 0.f;
            #pragma unroll
            for (int i = 0; i < 4; ++i) {
                float4 wv = wrow[lane + 64 * i];
                float4 hv = ((const float4*)h_lds)[lane + 64 * i];
                acc += wv.x*hv.x + wv.y*hv.y + wv.z*hv.z + wv.w*hv.w;
            }
            #pragma unroll
            for (int o = 32; o; o >>= 1) acc += __shfl_xor(acc, o);
            if (lane == 0) gh_lds[rr] = acc + bias_lds[rr];
        }
        __syncthreads();
        if (tid < 4) {
            float r = sigmoidf_(gir + gh_lds[tid]);
            float z = sigmoidf_(giz + gh_lds[4 + tid]);
            float n = tanhf(gin + r * gh_lds[8 + tid]);
            float hp = h_lds[j0 + tid];
            st_agent_f32(enc_outs + (size_t)t * 1024 + j0 + tid,
                         (1.f - z) * n + z * hp);
        }
        if (t < T - 1) {
            if (wid == 0) {
                asm volatile("s_waitcnt vmcnt(0)" ::: "memory");
                if (lane == 0) st_slot(slots + bid * 16, (unsigned)(t + 1));
                poll_slots(slots, (unsigned)(t + 1), lane);
            }
            __syncthreads();
        }
    }
}

// ------------------------- decoder recurrence ------------------------------
// 256 blocks x 512 threads; block b owns h indices [4b,4b+4) and s indices
// [2b,2b+2). LDS-resident: dec_W_ih, dec_W_hh (12 rows each), attn_W h-half
// (2 rows), M (4 rows). 3 slot exchanges per step.
// Critical-path layout per step:
//   wave0: s rows -> arrive b1 -> poll b1 -> softmax+x (alone) -> arrive b2
//          -> poll b2 ... gates -> arrive b3 -> poll b3
//   waves1-7: gh rows (overlap b1 wait); gi rows with everyone in phase C.
__global__ __launch_bounds__(512) void dec_seq(
    const float* __restrict__ Wih, const float* __restrict__ Whh,
    const float* __restrict__ bih, const float* __restrict__ bhh,
    const float* __restrict__ attnW,   // [512][2048]
    const float* __restrict__ attn_e,  // [512][512]
    const float* __restrict__ comb_e,  // [512][1024]
    const float* __restrict__ M,       // [1024][512]
    const float* __restrict__ enc_outs,
    float* __restrict__ H2,            // [512][1024]
    float* __restrict__ s_buf, float* __restrict__ x_buf,
    unsigned* __restrict__ slots)
{
    __shared__ float4 wih4[12 * 256];
    __shared__ float4 whh4[12 * 256];
    __shared__ float4 aw4[2 * 256];
    __shared__ float4 m4[4 * 128];
    __shared__ float h_lds[1024];
    __shared__ float x_lds[1024];
    __shared__ float p_lds[512];
    __shared__ float gh_lds[12], gi_lds[12];
    __shared__ float bih_lds[12], bhh_lds[12];

    const int tid = threadIdx.x, bid = blockIdx.x;
    const int j0 = bid * 4, l0 = bid * 2;
    for (int i = tid; i < 12 * 256; i += 512) {
        int r = i >> 8, c = i & 255;
        int grow = (r >> 2) * 1024 + j0 + (r & 3);
        wih4[i] = *(const float4*)(Wih + (size_t)grow * 1024 + c * 4);
        whh4[i] = *(const float4*)(Whh + (size_t)grow * 1024 + c * 4);
    }
    for (int i = tid; i < 2 * 256; i += 512) {
        int r = i >> 8, c = i & 255;
        aw4[i] = *(const float4*)(attnW + (size_t)(l0 + r) * 2048 + 1024 + c * 4);
    }
    for (int i = tid; i < 4 * 128; i += 512) {
        int r = i >> 7, c = i & 127;
        m4[i] = *(const float4*)(M + (size_t)(j0 + r) * 512 + c * 4);
    }
    if (tid < 12) {
        int grow = (tid >> 2) * 1024 + j0 + (tid & 3);
        bih_lds[tid] = bih[grow]; bhh_lds[tid] = bhh[grow];
    }
    __syncthreads();

    const int wid = tid >> 6, lane = tid & 63;
    for (int t = 0; t < T; ++t) {
        // ---- load h (previous step's h2, or encoder final) ----
        const float* hsrc = (t == 0) ? (enc_outs + (size_t)(T - 1) * 1024)
                                     : (H2 + (size_t)(t - 1) * 1024);
        ((float2*)h_lds)[tid] = ld_agent_f2(hsrc + tid * 2);
        float ae = 0.f, ce = 0.f;
        if (wid == 0 && (lane & 31) == 0)
            ae = attn_e[(size_t)t * 512 + l0 + (lane >> 5)];
        if (wid == 0 && (lane & 15) == 0)
            ce = comb_e[(size_t)t * 1024 + j0 + (lane >> 4)];
        __syncthreads();                            // (A) h_lds ready

        if (wid == 0) {
            // ---- phase A (wave0): 2 attention-score rows, 32 lanes each ----
            {
                int r = lane >> 5, q2 = lane & 31;
                const float4* arow = aw4 + r * 256;
                float acc = 0.f;
                #pragma unroll
                for (int i = 0; i < 8; ++i) {
                    float4 wv = arow[q2 + 32 * i];
                    float4 hv = ((const float4*)h_lds)[q2 + 32 * i];
                    acc += wv.x*hv.x + wv.y*hv.y + wv.z*hv.z + wv.w*hv.w;
                }
                #pragma unroll
                for (int o = 16; o; o >>= 1) acc += __shfl_xor(acc, o);
                if (q2 == 0) st_agent_f32(s_buf + l0 + r, acc + ae);
            }
            asm volatile("s_waitcnt vmcnt(0)" ::: "memory");
            if (lane == 0) st_slot(slots + bid * 16, (unsigned)(3 * t + 1));
            poll_slots(slots, (unsigned)(3 * t + 1), lane);

            // ---- phase B (wave0 alone): softmax(s) ; x = relu(ce + M@aw) ----
            float sv[8];
            {
                float2 v0 = ld_agent_f2(s_buf + lane * 8);
                float2 v1 = ld_agent_f2(s_buf + lane * 8 + 2);
                float2 v2 = ld_agent_f2(s_buf + lane * 8 + 4);
                float2 v3 = ld_agent_f2(s_buf + lane * 8 + 6);
                sv[0]=v0.x; sv[1]=v0.y; sv[2]=v1.x; sv[3]=v1.y;
                sv[4]=v2.x; sv[5]=v2.y; sv[6]=v3.x; sv[7]=v3.y;
            }
            float mx = sv[0];
            #pragma unroll
            for (int j = 1; j < 8; ++j) mx = fmaxf(mx, sv[j]);
            #pragma unroll
            for (int o = 32; o; o >>= 1) mx = fmaxf(mx, __shfl_xor(mx, o));
            float pv[8], ssum = 0.f;
            #pragma unroll
            for (int j = 0; j < 8; ++j) { pv[j] = expf(sv[j] - mx); ssum += pv[j]; }
            #pragma unroll
            for (int o = 32; o; o >>= 1) ssum += __shfl_xor(ssum, o);
            ((float4*)p_lds)[lane * 2]     = make_float4(pv[0], pv[1], pv[2], pv[3]);
            ((float4*)p_lds)[lane * 2 + 1] = make_float4(pv[4], pv[5], pv[6], pv[7]);
            asm volatile("s_waitcnt lgkmcnt(0)" ::: "memory");
            {
                int d = lane >> 4, q = lane & 15;
                const float4* mr = m4 + d * 128;
                float acc = 0.f;
                #pragma unroll
                for (int i = 0; i < 8; ++i) {
                    float4 mv = mr[q + 16 * i];
                    float4 pp = ((const float4*)p_lds)[q + 16 * i];
                    acc += mv.x*pp.x + mv.y*pp.y + mv.z*pp.z + mv.w*pp.w;
                }
                #pragma unroll
                for (int o = 8; o; o >>= 1) acc += __shfl_xor(acc, o);
                if (q == 0)
                    st_agent_f32(x_buf + j0 + d, fmaxf(ce + acc / ssum, 0.f));
            }
            asm volatile("s_waitcnt vmcnt(0)" ::: "memory");
            if (lane == 0) st_slot(slots + bid * 16, (unsigned)(3 * t + 2));
            poll_slots(slots, (unsigned)(3 * t + 2), lane);
        } else {
            // ---- phase A (waves 1-7): 12 gh rows, overlaps barrier waits ----
            for (int rr = wid - 1; rr < 12; rr += 7) {
                const float4* wrow = whh4 + rr * 256;
                float acc = 0.f;
                #pragma unroll
                for (int i = 0; i < 4; ++i) {
                    float4 wv = wrow[lane + 64 * i];
                    float4 hv = ((const float4*)h_lds)[lane + 64 * i];
                    acc += wv.x*hv.x + wv.y*hv.y + wv.z*hv.z + wv.w*hv.w;
                }
                #pragma unroll
                for (int o = 32; o; o >>= 1) acc += __shfl_xor(acc, o);
                if (lane == 0) gh_lds[rr] = acc + bhh_lds[rr];
            }
        }
        __syncthreads();                            // (B) x global-ready; gh done

        // ---- phase C: all waves ----
        ((float2*)x_lds)[tid] = ld_agent_f2(x_buf + tid * 2);
        __syncthreads();                            // (C) x_lds ready
        for (int rr = wid; rr < 12; rr += 8) {
            const float4* wrow = wih4 + rr * 256;
            float acc = 0.f;
            #pragma unroll
            for (int i = 0; i < 4; ++i) {
                float4 wv = wrow[lane + 64 * i];
                float4 xv = ((const float4*)x_lds)[lane + 64 * i];
                acc += wv.x*xv.x + wv.y*xv.y + wv.z*xv.z + wv.w*xv.w;
            }
            #pragma unroll
            for (int o = 32; o; o >>= 1) acc += __shfl_xor(acc, o);
            if (lane == 0) gi_lds[rr] = acc + bih_lds[rr];
        }
        __syncthreads();                            // (D) gi ready
        if (tid < 4) {
            float r = sigmoidf_(gi_lds[tid] + gh_lds[tid]);
            float z = sigmoidf_(gi_lds[4 + tid] + gh_lds[4 + tid]);
            float n = tanhf(gi_lds[8 + tid] + r * gh_lds[8 + tid]);
            float hp = h_lds[j0 + tid];
            st_agent_f32(H2 + (size_t)t * 1024 + j0 + tid,
                         (1.f - z) * n + z * hp);
        }
        if (t < T - 1) {
            if (wid == 0) {
                asm volatile("s_waitcnt vmcnt(0)" ::: "memory");
                if (lane == 0) st_slot(slots + bid * 16, (unsigned)(3 * t + 3));
                poll_slots(slots, (unsigned)(3 * t + 3), lane);
            }
            __syncthreads();                        // (E)
        }
    }
}

// ------------------- output GEMM + fused LSE partials ----------------------
// grid (250, 4), block 256; tile 128(cols) x 128(rows), thread 8x8.
__global__ __launch_bounds__(256) void out_gemm_lse(
    const float* __restrict__ H2, const float* __restrict__ outW,
    const float* __restrict__ outB, const int* __restrict__ tgt,
    float* __restrict__ lsep, float* __restrict__ tgtlog)
{
    __shared__ float A_lds[32][128];
    __shared__ float B_lds[32][128];
    const int tid = threadIdx.x;
    const int tx = tid & 15, ty = tid >> 4;
    const int c0 = blockIdx.x * 128, r0 = blockIdx.y * 128;
    float acc[8][8] = {};

    for (int k0 = 0; k0 < 1024; k0 += 32) {
        #pragma unroll
        for (int q = 0; q < 4; ++q) {
            int f4 = tid + q * 256;          // 0..1023
            int row = f4 >> 3, c4 = f4 & 7;
            float4 a = *(const float4*)(H2 + (size_t)(r0 + row) * 1024 + k0 + c4 * 4);
            A_lds[c4*4+0][row] = a.x; A_lds[c4*4+1][row] = a.y;
            A_lds[c4*4+2][row] = a.z; A_lds[c4*4+3][row] = a.w;
            float4 b = *(const float4*)(outW + (size_t)(c0 + row) * 1024 + k0 + c4 * 4);
            B_lds[c4*4+0][row] = b.x; B_lds[c4*4+1][row] = b.y;
            B_lds[c4*4+2][row] = b.z; B_lds[c4*4+3][row] = b.w;
        }
        __syncthreads();
        #pragma unroll
        for (int kk = 0; kk < 32; ++kk) {
            float4 a0 = *(const float4*)&A_lds[kk][ty * 8];
            float4 a1 = *(const float4*)&A_lds[kk][ty * 8 + 4];
            float4 b0 = *(const float4*)&B_lds[kk][tx * 8];
            float4 b1 = *(const float4*)&B_lds[kk][tx * 8 + 4];
            float av[8] = {a0.x,a0.y,a0.z,a0.w,a1.x,a1.y,a1.z,a1.w};
            float bv[8] = {b0.x,b0.y,b0.z,b0.w,b1.x,b1.y,b1.z,b1.w};
            #pragma unroll
            for (int i = 0; i < 8; ++i)
                #pragma unroll
                for (int j = 0; j < 8; ++j)
                    acc[i][j] = fmaf(av[i], bv[j], acc[i][j]);
        }
        __syncthreads();
    }
    float bj[8];
    #pragma unroll
    for (int j = 0; j < 8; ++j) bj[j] = outB[c0 + tx * 8 + j];

    const int bx = blockIdx.x;
    #pragma unroll
    for (int i = 0; i < 8; ++i) {
        int t = r0 + ty * 8 + i;
        float rowv[8];
        float vmax = -INFINITY;
        #pragma unroll
        for (int j = 0; j < 8; ++j) {
            rowv[j] = acc[i][j] + bj[j];
            vmax = fmaxf(vmax, rowv[j]);
        }
        float ssum = 0.f;
        #pragma unroll
        for (int j = 0; j < 8; ++j) ssum += expf(rowv[j] - vmax);
        #pragma unroll
        for (int o = 1; o < 16; o <<= 1) {
            float om = __shfl_xor(vmax, o);
            float os = __shfl_xor(ssum, o);
            float nm = fmaxf(vmax, om);
            ssum = ssum * expf(vmax - nm) + os * expf(om - nm);
            vmax = nm;
        }
        if (tx == 0)
            *(float2*)&lsep[((size_t)t * 250 + bx) * 2] = make_float2(vmax, ssum);
        int tv = tgt[t];
        if (tv >= c0 && tv < c0 + 128) {
            int rel = tv - c0;
            if ((rel >> 3) == tx) tgtlog[t] = rowv[rel & 7];
        }
    }
}

// ------------------------- final combine -----------------------------------
__global__ __launch_bounds__(512) void lse_combine(
    const float* __restrict__ lsep, const float* __restrict__ tgtlog,
    float* __restrict__ out)
{
    const int t = threadIdx.x;     // 0..511
    float m = -INFINITY, s = 0.f;
    for (int cb = 0; cb < 250; ++cb) {
        float2 p = *(const float2*)&lsep[((size_t)t * 250 + cb) * 2];
        float nm = fmaxf(m, p.x);
        s = s * expf(m - nm) + p.y * expf(p.x - nm);
        m = nm;
    }
    float nll = (m + logf(s)) - tgtlog[t];
    __shared__ float red[8];
    float v = nll;
    #pragma unroll
    for (int o = 32; o; o >>= 1) v += __shfl_xor(v, o);
    if ((t & 63) == 0) red[t >> 6] = v;
    __syncthreads();
    if (t == 0) {
        float sum = 0.f;
        for (int w = 0; w < 8; ++w) sum += red[w];
        out[0] = sum / 512.f;
    }
}

// ---------------------------------------------------------------------------
extern "C" void kernel_launch(void* const* d_in, const int* in_sizes, int n_in,
                              void* d_out, int out_size, void* d_ws, size_t ws_size,
                              hipStream_t stream) {
    const int*   input   = (const int*)d_in[0];
    const int*   target  = (const int*)d_in[1];
    const float* enc_emb = (const float*)d_in[2];
    const float* eWih    = (const float*)d_in[3];
    const float* eWhh    = (const float*)d_in[4];
    const float* ebih    = (const float*)d_in[5];
    const float* ebhh    = (const float*)d_in[6];
    const float* dec_emb = (const float*)d_in[7];
    const float* attnW   = (const float*)d_in[8];
    const float* attnB   = (const float*)d_in[9];
    const float* combW   = (const float*)d_in[10];
    const float* combB   = (const float*)d_in[11];
    const float* dWih    = (const float*)d_in[12];
    const float* dWhh    = (const float*)d_in[13];
    const float* dbih    = (const float*)d_in[14];
    const float* dbhh    = (const float*)d_in[15];
    const float* outW    = (const float*)d_in[16];
    const float* outB    = (const float*)d_in[17];
    float* out = (float*)d_out;

    float* wsf = (float*)d_ws;
    unsigned* slotsE = (unsigned*)d_ws;                       // bytes [0,16384)
    unsigned* slotsD = (unsigned*)((char*)d_ws + 16384);      // bytes [16384,32768)
    float* enc_gi   = wsf + 8192;      // [512][3072]
    float* enc_outs = wsf + 1581056;   // [512][1024]
    float* attn_e   = wsf + 2105344;   // [512][512]
    float* comb_e   = wsf + 2367488;   // [512][1024]
    float* Mws      = wsf + 2891776;   // [1024][512]
    float* H2       = wsf + 3416064;   // [512][1024]
    float* s_buf    = wsf + 3940352;   // [512]
    float* x_buf    = wsf + 3940864;   // [1024]
    float* lsep     = wsf + 3941888;   // [512][250][2]
    float* tgtlog   = wsf + 4197888;   // [512]

    hipMemsetAsync(d_ws, 0, 32768, stream);   // barrier slots

    // K1: token-indexed precomputes
    gemm_tn<<<dim3(48, 8), 256, 0, stream>>>(enc_emb, 1024, 0, input, 1,
        eWih, 1024, 0, ebih, enc_gi, 3072, 1024);
    gemm_tn<<<dim3(8, 8), 256, 0, stream>>>(dec_emb, 1024, 0, target, 2,
        attnW, 2048, 0, attnB, attn_e, 512, 1024);
    gemm_tn<<<dim3(16, 8), 256, 0, stream>>>(dec_emb, 1024, 0, target, 2,
        combW, 2048, 0, combB, comb_e, 1024, 1024);

    // K2: encoder recurrence
    enc_seq<<<256, 512, 0, stream>>>(eWhh, ebhh, enc_gi, enc_outs, slotsE);

    // K3: M = comb_W[:, H:] @ enc_outs^T
    gemm_tn<<<dim3(8, 16), 256, 0, stream>>>(combW, 2048, 1024, nullptr, 0,
        enc_outs, 1024, 0, nullptr, Mws, 512, 1024);

    // K4: decoder recurrence
    dec_seq<<<256, 512, 0, stream>>>(dWih, dWhh, dbih, dbhh, attnW,
        attn_e, comb_e, Mws, enc_outs, H2, s_buf, x_buf, slotsD);

    // K5: logits GEMM + fused LSE partials
    out_gemm_lse<<<dim3(250, 4), 256, 0, stream>>>(H2, outW, outB, target,
        lsep, tgtlog);

    // K6: combine -> scalar
    lse_combine<<<1, 512, 0, stream>>>(lsep, tgtlog, out);
}